// Round 2
// baseline (965.783 us; speedup 1.0000x reference)
//
#include <hip/hip_runtime.h>

typedef unsigned short u16;
typedef __attribute__((ext_vector_type(8))) short bf16x8;
typedef __attribute__((ext_vector_type(4))) float f32x4;

#define B_SZ   2
#define L_SZ   2048
#define DM     1024
#define DI     2048
#define NST    16
#define RNK    64
#define TOK    (B_SZ * L_SZ)   // 4096

__device__ __forceinline__ float bf2f(u16 u) {
    return __uint_as_float(((unsigned int)u) << 16);
}
__device__ __forceinline__ u16 f2bf(float f) {
    unsigned int x = __float_as_uint(f);
    x += 0x7fffu + ((x >> 16) & 1u);   // RNE
    return (u16)(x >> 16);
}
__device__ __forceinline__ void bf2x2(unsigned int p, float& lo, float& hi) {
    lo = __uint_as_float(p << 16);
    hi = __uint_as_float(p & 0xffff0000u);
}
__device__ __forceinline__ float silu(float v) {
    return v / (1.f + __expf(-v));
}

// ---------------------------------------------------------------------------
// f32 -> bf16 conversion (vectorized x4); n4 = elements/4
// ---------------------------------------------------------------------------
__global__ __launch_bounds__(256)
void cvt_f2b(const float* __restrict__ src, u16* __restrict__ dst, int n4)
{
    const int i = blockIdx.x * 256 + threadIdx.x;
    if (i < n4) {
        const float4 v = ((const float4*)src)[i];
        ushort4 o;
        o.x = f2bf(v.x); o.y = f2bf(v.y); o.z = f2bf(v.z); o.w = f2bf(v.w);
        ((ushort4*)dst)[i] = o;
    }
}

// ---------------------------------------------------------------------------
// GEMM  C[M][N] = A[M][K] @ B[N][K]^T   (both operands K-contiguous bf16)
// 128x128 tile, BK=32, 4 waves (2x2 of 64x64), mfma_f32_16x16x32_bf16.
// EPI==0: plain f32 store to outF (ld = N)   [final out_proj]
// EPI==1: in_proj epilogue: col<DI -> out0=x_m (bf16); col>=DI -> out1=silu (bf16)
// ---------------------------------------------------------------------------
template<int EPI>
__global__ __launch_bounds__(256, 2)
void gemm_bt(const u16* __restrict__ A, const u16* __restrict__ B,
             const int K, const int N,
             u16* __restrict__ out0, u16* __restrict__ out1,
             float* __restrict__ outF)
{
    __shared__ u16 sA[128 * 40];   // 32 k-elems padded to 40 (2-way conflicts only)
    __shared__ u16 sB[128 * 40];

    const int tid  = threadIdx.x;
    const int rowBase = blockIdx.x << 7;
    const int colBase = blockIdx.y << 7;
    const int wave = tid >> 6, lane = tid & 63;
    const int wm = (wave >> 1) << 6;          // 0 / 64
    const int wn = (wave & 1) << 6;           // 0 / 64
    const int lrow = lane & 15, quad = lane >> 4;

    // staging map: thread -> (row = tid>>2, kchunk = tid&3), second rep row+64
    const int sr  = tid >> 2;
    const int skc = tid & 3;
    const u16* Ap = A + (size_t)(rowBase + sr) * K + skc * 8;
    const u16* Bp = B + (size_t)(colBase + sr) * K + skc * 8;
    const size_t rowJump = (size_t)64 * K;
    const int sLds = sr * 40 + skc * 8;

    f32x4 acc[4][4];
#pragma unroll
    for (int i = 0; i < 4; ++i)
#pragma unroll
        for (int j = 0; j < 4; ++j) acc[i][j] = (f32x4){0.f, 0.f, 0.f, 0.f};

    uint4 pa0 = *(const uint4*)(Ap);
    uint4 pa1 = *(const uint4*)(Ap + rowJump);
    uint4 pb0 = *(const uint4*)(Bp);
    uint4 pb1 = *(const uint4*)(Bp + rowJump);

    const int KT = K >> 5;
    for (int kt = 0; kt < KT; ++kt) {
        *(uint4*)&sA[sLds]           = pa0;
        *(uint4*)&sA[sLds + 64 * 40] = pa1;
        *(uint4*)&sB[sLds]           = pb0;
        *(uint4*)&sB[sLds + 64 * 40] = pb1;
        __syncthreads();

        if (kt + 1 < KT) {                     // prefetch next tile into regs
            const int ko = (kt + 1) * 32;
            pa0 = *(const uint4*)(Ap + ko);
            pa1 = *(const uint4*)(Ap + ko + rowJump);
            pb0 = *(const uint4*)(Bp + ko);
            pb1 = *(const uint4*)(Bp + ko + rowJump);
        }

        bf16x8 af[4], bfr[4];
#pragma unroll
        for (int i = 0; i < 4; ++i)
            af[i] = *(const bf16x8*)&sA[(wm + i * 16 + lrow) * 40 + quad * 8];
#pragma unroll
        for (int j = 0; j < 4; ++j)
            bfr[j] = *(const bf16x8*)&sB[(wn + j * 16 + lrow) * 40 + quad * 8];

#pragma unroll
        for (int i = 0; i < 4; ++i)
#pragma unroll
            for (int j = 0; j < 4; ++j)
                acc[i][j] = __builtin_amdgcn_mfma_f32_16x16x32_bf16(
                    af[i], bfr[j], acc[i][j], 0, 0, 0);
        __syncthreads();
    }

    // epilogue: C/D layout col=lane&15, row=quad*4+reg
#pragma unroll
    for (int i = 0; i < 4; ++i) {
#pragma unroll
        for (int j = 0; j < 4; ++j) {
            const int gcol = colBase + wn + j * 16 + lrow;
#pragma unroll
            for (int r = 0; r < 4; ++r) {
                const int grow = rowBase + wm + i * 16 + quad * 4 + r;
                const float v = acc[i][j][r];
                if (EPI == 0) {
                    outF[(size_t)grow * N + gcol] = v;
                } else {
                    if (gcol < DI) out0[(size_t)grow * DI + gcol] = f2bf(v);
                    else           out1[(size_t)grow * DI + (gcol - DI)] = f2bf(silu(v));
                }
            }
        }
    }
}

// ---------------------------------------------------------------------------
// causal depthwise conv (K=4) + silu:  xc[t][ch] = silu(b + sum_j w[j]*xm[t-3+j][ch])
// ---------------------------------------------------------------------------
__global__ __launch_bounds__(256)
void conv_silu_kernel(const u16* __restrict__ xm, const float* __restrict__ cw,
                      const float* __restrict__ cb, u16* __restrict__ xc)
{
    const int idx = blockIdx.x * 256 + threadIdx.x;     // [0, TOK*DI)
    const int ch = idx & (DI - 1);
    const int t  = idx >> 11;                            // DI = 2^11
    const int l  = t & (L_SZ - 1);

    const float4 wv = *(const float4*)(cw + ch * 4);

    float acc = cb[ch];
    if (l >= 3) acc += wv.x * bf2f(xm[(size_t)(t - 3) * DI + ch]);
    if (l >= 2) acc += wv.y * bf2f(xm[(size_t)(t - 2) * DI + ch]);
    if (l >= 1) acc += wv.z * bf2f(xm[(size_t)(t - 1) * DI + ch]);
    acc += wv.w * bf2f(xm[(size_t)t * DI + ch]);

    xc[idx] = f2bf(silu(acc));
}

// ---------------------------------------------------------------------------
// x_dbl[t][0:96] = xc[t][:] @ W_x[n][:]^T   (K=2048, N=96) — block per token
// ---------------------------------------------------------------------------
__global__ __launch_bounds__(256)
void xdbl_kernel(const u16* __restrict__ xc, const u16* __restrict__ Wx,
                 float* __restrict__ xdbl)
{
    __shared__ float sx[DI];
    const int t = blockIdx.x;
    const int tid = threadIdx.x;
    const u16* xrow = xc + (size_t)t * DI;
    {
        const int k = tid * 8;
        uint4 v = *(const uint4*)(xrow + k);
        float f0, f1, f2, f3, f4, f5, f6, f7;
        bf2x2(v.x, f0, f1); bf2x2(v.y, f2, f3);
        bf2x2(v.z, f4, f5); bf2x2(v.w, f6, f7);
        sx[k] = f0; sx[k+1] = f1; sx[k+2] = f2; sx[k+3] = f3;
        sx[k+4] = f4; sx[k+5] = f5; sx[k+6] = f6; sx[k+7] = f7;
    }
    __syncthreads();

    const int n = tid >> 1, half = tid & 1;
    float acc = 0.f;
    if (n < 96) {
        const u16* wrow = Wx + (size_t)n * DI + half * 1024;
        const float* xr = sx + half * 1024;
#pragma unroll 4
        for (int k = 0; k < 1024; k += 8) {
            uint4 wv = *(const uint4*)(wrow + k);
            float a0, a1, a2, a3, a4, a5, a6, a7;
            bf2x2(wv.x, a0, a1); bf2x2(wv.y, a2, a3);
            bf2x2(wv.z, a4, a5); bf2x2(wv.w, a6, a7);
            acc += xr[k]*a0 + xr[k+1]*a1 + xr[k+2]*a2 + xr[k+3]*a3
                 + xr[k+4]*a4 + xr[k+5]*a5 + xr[k+6]*a6 + xr[k+7]*a7;
        }
        acc += __shfl_xor(acc, 1, 64);
        if (half == 0) xdbl[(size_t)t * 96 + n] = acc;
    }
}

// ---------------------------------------------------------------------------
// delta[t][ch] = softplus(xdbl[t][0:64] @ W_dt[ch][:]^T + b_dt[ch])
// grid (TOK, DI/256)
// ---------------------------------------------------------------------------
__global__ __launch_bounds__(256)
void delta_kernel(const float* __restrict__ xdbl, const u16* __restrict__ Wdt,
                  const float* __restrict__ bdt, float* __restrict__ delta)
{
    __shared__ float sd[64];
    const int t = blockIdx.x;
    if (threadIdx.x < 64) sd[threadIdx.x] = xdbl[(size_t)t * 96 + threadIdx.x];
    __syncthreads();

    const int ch = blockIdx.y * 256 + threadIdx.x;
    const u16* wrow = Wdt + (size_t)ch * RNK;
    float acc = bdt[ch];
#pragma unroll
    for (int r = 0; r < RNK; r += 8) {
        uint4 wv = *(const uint4*)(wrow + r);
        float a0, a1, a2, a3, a4, a5, a6, a7;
        bf2x2(wv.x, a0, a1); bf2x2(wv.y, a2, a3);
        bf2x2(wv.z, a4, a5); bf2x2(wv.w, a6, a7);
        acc += sd[r]*a0 + sd[r+1]*a1 + sd[r+2]*a2 + sd[r+3]*a3
             + sd[r+4]*a4 + sd[r+5]*a5 + sd[r+6]*a6 + sd[r+7]*a7;
    }
    const float sp = (acc > 20.f) ? acc : log1pf(__expf(acc));
    delta[(size_t)t * DI + ch] = sp;
}

// ---------------------------------------------------------------------------
// selective scan. block = 256 thr = 16 channels x 16 states; grid (DI/16, B)
// h = exp(delta*A)*h + delta*x*B ; y = sum_n h*C ; yfin = (y + D*x)*silu(res)
// ---------------------------------------------------------------------------
#define CHUNK 64
__global__ __launch_bounds__(256)
void scan_kernel(const float* __restrict__ delta, const float* __restrict__ xdbl,
                 const u16* __restrict__ xc, const u16* __restrict__ sres,
                 const float* __restrict__ A_log, const float* __restrict__ Dp,
                 u16* __restrict__ yfin)
{
    const int b   = blockIdx.y;
    const int ch0 = blockIdx.x * 16;
    const int tid = threadIdx.x;
    const int chl = tid >> 4, n = tid & 15;
    const int ch  = ch0 + chl;

    const float Aval = -__expf(A_log[ch * NST + n]);
    const float Dval = Dp[ch];

    __shared__ float s_d[CHUNK][16], s_x[CHUNK][16], s_B[CHUNK][16],
                     s_C[CHUNK][16], s_r[CHUNK][16];

    float h = 0.f;
    for (int l0 = 0; l0 < L_SZ; l0 += CHUNK) {
        __syncthreads();
#pragma unroll
        for (int j = 0; j < (CHUNK * 16) / 256; ++j) {
            const int idx = j * 256 + tid;
            const int i = idx >> 4, c = idx & 15;
            const size_t tok = (size_t)(b * L_SZ + l0 + i);
            s_d[i][c] = delta[tok * DI + ch0 + c];
            s_x[i][c] = bf2f(xc[tok * DI + ch0 + c]);
            s_r[i][c] = bf2f(sres[tok * DI + ch0 + c]);
            s_B[i][c] = xdbl[tok * 96 + 64 + c];
            s_C[i][c] = xdbl[tok * 96 + 80 + c];
        }
        __syncthreads();

        for (int i = 0; i < CHUNK; ++i) {
            const float d  = s_d[i][chl];
            const float xv = s_x[i][chl];
            const float dA = __expf(d * Aval);
            h = dA * h + (d * xv) * s_B[i][n];
            float p = h * s_C[i][n];
            p += __shfl_xor(p, 1, 16);
            p += __shfl_xor(p, 2, 16);
            p += __shfl_xor(p, 4, 16);
            p += __shfl_xor(p, 8, 16);
            if (n == 0) {
                const float y = (p + Dval * xv) * s_r[i][chl];
                yfin[(size_t)(b * L_SZ + l0 + i) * DI + ch] = f2bf(y);
            }
        }
    }
}

// ---------------------------------------------------------------------------
extern "C" void kernel_launch(void* const* d_in, const int* in_sizes, int n_in,
                              void* d_out, int out_size, void* d_ws, size_t ws_size,
                              hipStream_t stream)
{
    const float* x      = (const float*)d_in[0];
    const float* W_in   = (const float*)d_in[1];
    const float* conv_w = (const float*)d_in[2];
    const float* conv_b = (const float*)d_in[3];
    const float* W_x    = (const float*)d_in[4];
    const float* W_dt   = (const float*)d_in[5];
    const float* b_dt   = (const float*)d_in[6];
    const float* A_log  = (const float*)d_in[7];
    const float* D_par  = (const float*)d_in[8];
    const float* W_out  = (const float*)d_in[9];
    float* out = (float*)d_out;

    char* ws = (char*)d_ws;
    size_t off = 0;
    u16* xb    = (u16*)(ws + off); off += (size_t)TOK * DM * 2;        //  8.4 MB
    u16* Winb  = (u16*)(ws + off); off += (size_t)(2 * DI) * DM * 2;   //  8.4 MB
    u16* Woutb = (u16*)(ws + off); off += (size_t)DM * DI * 2;         //  4.2 MB
    u16* Wxb   = (u16*)(ws + off); off += (size_t)96 * DI * 2;         //  0.4 MB
    u16* Wdtb  = (u16*)(ws + off); off += (size_t)DI * RNK * 2;        //  0.3 MB
    u16* xm    = (u16*)(ws + off); off += (size_t)TOK * DI * 2;        // 16.8 MB
    u16* xc    = (u16*)(ws + off); off += (size_t)TOK * DI * 2;        // 16.8 MB
    u16* sres  = (u16*)(ws + off); off += (size_t)TOK * DI * 2;        // 16.8 MB
    u16* yfin  = (u16*)(ws + off); off += (size_t)TOK * DI * 2;        // 16.8 MB
    float* xdbl  = (float*)(ws + off); off += (size_t)TOK * 96 * 4;    //  1.6 MB
    float* delta = (float*)(ws + off); off += (size_t)TOK * DI * 4;    // 33.6 MB

    // 0. convert GEMM operands f32 -> bf16
    cvt_f2b<<<(TOK * DM / 4 + 255) / 256, 256, 0, stream>>>(x, xb, TOK * DM / 4);
    cvt_f2b<<<(2 * DI * DM / 4 + 255) / 256, 256, 0, stream>>>(W_in, Winb, 2 * DI * DM / 4);
    cvt_f2b<<<(DM * DI / 4 + 255) / 256, 256, 0, stream>>>(W_out, Woutb, DM * DI / 4);
    cvt_f2b<<<(96 * DI / 4 + 255) / 256, 256, 0, stream>>>(W_x, Wxb, 96 * DI / 4);
    cvt_f2b<<<(DI * RNK / 4 + 255) / 256, 256, 0, stream>>>(W_dt, Wdtb, DI * RNK / 4);

    // 1. in_proj: [4096x1024] @ [1024x4096]^T -> x_m (bf16) + silu(res) (bf16)
    gemm_bt<1><<<dim3(TOK / 128, (2 * DI) / 128), 256, 0, stream>>>(
        xb, Winb, DM, 2 * DI, xm, sres, nullptr);

    // 2. causal depthwise conv + silu
    conv_silu_kernel<<<(TOK * DI) / 256, 256, 0, stream>>>(xm, conv_w, conv_b, xc);

    // 3. x_dbl = xc @ W_x^T  [4096 x 96]
    xdbl_kernel<<<TOK, 256, 0, stream>>>(xc, Wxb, xdbl);

    // 4. delta = softplus(dlt @ W_dt^T + b_dt)  [4096 x 2048]
    delta_kernel<<<dim3(TOK, DI / 256), 256, 0, stream>>>(xdbl, Wdtb, b_dt, delta);

    // 5. selective scan -> yfin (bf16)
    scan_kernel<<<dim3(DI / 16, B_SZ), 256, 0, stream>>>(
        delta, xdbl, xc, sres, A_log, D_par, yfin);

    // 6. out = yfin @ W_out^T  [4096 x 1024] (f32 store)
    gemm_bt<0><<<dim3(TOK / 128, DM / 128), 256, 0, stream>>>(
        yfin, Woutb, DI, DM, nullptr, nullptr, out);
}

// Round 3
// 620.427 us; speedup vs baseline: 1.5566x; 1.5566x over previous
//
#include <hip/hip_runtime.h>

typedef unsigned short u16;
typedef __attribute__((ext_vector_type(8))) short bf16x8;
typedef __attribute__((ext_vector_type(4))) float f32x4;

#define B_SZ   2
#define L_SZ   2048
#define DM     1024
#define DI     2048
#define NST    16
#define RNK    64
#define TOK    (B_SZ * L_SZ)   // 4096
#define NC     32              // scan chunks
#define CLEN   (L_SZ / NC)     // 64 steps per chunk

__device__ __forceinline__ float bf2f(u16 u) {
    return __uint_as_float(((unsigned int)u) << 16);
}
__device__ __forceinline__ u16 f2bf(float f) {
    unsigned int x = __float_as_uint(f);
    x += 0x7fffu + ((x >> 16) & 1u);   // RNE
    return (u16)(x >> 16);
}
__device__ __forceinline__ void bf2x2(unsigned int p, float& lo, float& hi) {
    lo = __uint_as_float(p << 16);
    hi = __uint_as_float(p & 0xffff0000u);
}
__device__ __forceinline__ float silu(float v) {
    return v / (1.f + __expf(-v));
}

// ---------------------------------------------------------------------------
// f32 -> bf16 conversion (vectorized x4); n4 = elements/4
// ---------------------------------------------------------------------------
__global__ __launch_bounds__(256)
void cvt_f2b(const float* __restrict__ src, u16* __restrict__ dst, int n4)
{
    const int i = blockIdx.x * 256 + threadIdx.x;
    if (i < n4) {
        const float4 v = ((const float4*)src)[i];
        ushort4 o;
        o.x = f2bf(v.x); o.y = f2bf(v.y); o.z = f2bf(v.z); o.w = f2bf(v.w);
        ((ushort4*)dst)[i] = o;
    }
}

// ---------------------------------------------------------------------------
// GEMM  C[M][N] = A[M][K] @ B[N][K]^T   (both operands K-contiguous bf16)
// 128x128 tile, BK=32, 4 waves (2x2 of 64x64), mfma_f32_16x16x32_bf16.
// EPI==0: plain f32 store to outF (ld = N)   [final out_proj]
// EPI==1: in_proj epilogue: col<DI -> out0=x_m (bf16); col>=DI -> out1=silu (bf16)
// ---------------------------------------------------------------------------
template<int EPI>
__global__ __launch_bounds__(256, 2)
void gemm_bt(const u16* __restrict__ A, const u16* __restrict__ B,
             const int K, const int N,
             u16* __restrict__ out0, u16* __restrict__ out1,
             float* __restrict__ outF)
{
    __shared__ u16 sA[128 * 40];   // 32 k-elems padded to 40 (2-way conflicts only)
    __shared__ u16 sB[128 * 40];

    const int tid  = threadIdx.x;
    const int rowBase = blockIdx.x << 7;
    const int colBase = blockIdx.y << 7;
    const int wave = tid >> 6, lane = tid & 63;
    const int wm = (wave >> 1) << 6;          // 0 / 64
    const int wn = (wave & 1) << 6;           // 0 / 64
    const int lrow = lane & 15, quad = lane >> 4;

    const int sr  = tid >> 2;
    const int skc = tid & 3;
    const u16* Ap = A + (size_t)(rowBase + sr) * K + skc * 8;
    const u16* Bp = B + (size_t)(colBase + sr) * K + skc * 8;
    const size_t rowJump = (size_t)64 * K;
    const int sLds = sr * 40 + skc * 8;

    f32x4 acc[4][4];
#pragma unroll
    for (int i = 0; i < 4; ++i)
#pragma unroll
        for (int j = 0; j < 4; ++j) acc[i][j] = (f32x4){0.f, 0.f, 0.f, 0.f};

    uint4 pa0 = *(const uint4*)(Ap);
    uint4 pa1 = *(const uint4*)(Ap + rowJump);
    uint4 pb0 = *(const uint4*)(Bp);
    uint4 pb1 = *(const uint4*)(Bp + rowJump);

    const int KT = K >> 5;
    for (int kt = 0; kt < KT; ++kt) {
        *(uint4*)&sA[sLds]           = pa0;
        *(uint4*)&sA[sLds + 64 * 40] = pa1;
        *(uint4*)&sB[sLds]           = pb0;
        *(uint4*)&sB[sLds + 64 * 40] = pb1;
        __syncthreads();

        if (kt + 1 < KT) {
            const int ko = (kt + 1) * 32;
            pa0 = *(const uint4*)(Ap + ko);
            pa1 = *(const uint4*)(Ap + ko + rowJump);
            pb0 = *(const uint4*)(Bp + ko);
            pb1 = *(const uint4*)(Bp + ko + rowJump);
        }

        bf16x8 af[4], bfr[4];
#pragma unroll
        for (int i = 0; i < 4; ++i)
            af[i] = *(const bf16x8*)&sA[(wm + i * 16 + lrow) * 40 + quad * 8];
#pragma unroll
        for (int j = 0; j < 4; ++j)
            bfr[j] = *(const bf16x8*)&sB[(wn + j * 16 + lrow) * 40 + quad * 8];

#pragma unroll
        for (int i = 0; i < 4; ++i)
#pragma unroll
            for (int j = 0; j < 4; ++j)
                acc[i][j] = __builtin_amdgcn_mfma_f32_16x16x32_bf16(
                    af[i], bfr[j], acc[i][j], 0, 0, 0);
        __syncthreads();
    }

#pragma unroll
    for (int i = 0; i < 4; ++i) {
#pragma unroll
        for (int j = 0; j < 4; ++j) {
            const int gcol = colBase + wn + j * 16 + lrow;
#pragma unroll
            for (int r = 0; r < 4; ++r) {
                const int grow = rowBase + wm + i * 16 + quad * 4 + r;
                const float v = acc[i][j][r];
                if (EPI == 0) {
                    outF[(size_t)grow * N + gcol] = v;
                } else {
                    if (gcol < DI) out0[(size_t)grow * DI + gcol] = f2bf(v);
                    else           out1[(size_t)grow * DI + (gcol - DI)] = f2bf(silu(v));
                }
            }
        }
    }
}

// ---------------------------------------------------------------------------
// causal depthwise conv (K=4) + silu
// ---------------------------------------------------------------------------
__global__ __launch_bounds__(256)
void conv_silu_kernel(const u16* __restrict__ xm, const float* __restrict__ cw,
                      const float* __restrict__ cb, u16* __restrict__ xc)
{
    const int idx = blockIdx.x * 256 + threadIdx.x;     // [0, TOK*DI)
    const int ch = idx & (DI - 1);
    const int t  = idx >> 11;
    const int l  = t & (L_SZ - 1);

    const float4 wv = *(const float4*)(cw + ch * 4);

    float acc = cb[ch];
    if (l >= 3) acc += wv.x * bf2f(xm[(size_t)(t - 3) * DI + ch]);
    if (l >= 2) acc += wv.y * bf2f(xm[(size_t)(t - 2) * DI + ch]);
    if (l >= 1) acc += wv.z * bf2f(xm[(size_t)(t - 1) * DI + ch]);
    acc += wv.w * bf2f(xm[(size_t)t * DI + ch]);

    xc[idx] = f2bf(silu(acc));
}

// ---------------------------------------------------------------------------
// x_dbl[t][0:96] = xc[t][:] @ W_x[n][:]^T   (K=2048, N=96) — block per token
// ---------------------------------------------------------------------------
__global__ __launch_bounds__(256)
void xdbl_kernel(const u16* __restrict__ xc, const u16* __restrict__ Wx,
                 float* __restrict__ xdbl)
{
    __shared__ float sx[DI];
    const int t = blockIdx.x;
    const int tid = threadIdx.x;
    const u16* xrow = xc + (size_t)t * DI;
    {
        const int k = tid * 8;
        uint4 v = *(const uint4*)(xrow + k);
        float f0, f1, f2, f3, f4, f5, f6, f7;
        bf2x2(v.x, f0, f1); bf2x2(v.y, f2, f3);
        bf2x2(v.z, f4, f5); bf2x2(v.w, f6, f7);
        sx[k] = f0; sx[k+1] = f1; sx[k+2] = f2; sx[k+3] = f3;
        sx[k+4] = f4; sx[k+5] = f5; sx[k+6] = f6; sx[k+7] = f7;
    }
    __syncthreads();

    const int n = tid >> 1, half = tid & 1;
    float acc = 0.f;
    if (n < 96) {
        const u16* wrow = Wx + (size_t)n * DI + half * 1024;
        const float* xr = sx + half * 1024;
#pragma unroll 4
        for (int k = 0; k < 1024; k += 8) {
            uint4 wv = *(const uint4*)(wrow + k);
            float a0, a1, a2, a3, a4, a5, a6, a7;
            bf2x2(wv.x, a0, a1); bf2x2(wv.y, a2, a3);
            bf2x2(wv.z, a4, a5); bf2x2(wv.w, a6, a7);
            acc += xr[k]*a0 + xr[k+1]*a1 + xr[k+2]*a2 + xr[k+3]*a3
                 + xr[k+4]*a4 + xr[k+5]*a5 + xr[k+6]*a6 + xr[k+7]*a7;
        }
        acc += __shfl_xor(acc, 1, 64);
        if (half == 0) xdbl[(size_t)t * 96 + n] = acc;
    }
}

// ---------------------------------------------------------------------------
// delta[t][ch] = softplus(xdbl[t][0:64] @ W_dt[ch][:]^T + b_dt[ch])
// ---------------------------------------------------------------------------
__global__ __launch_bounds__(256)
void delta_kernel(const float* __restrict__ xdbl, const u16* __restrict__ Wdt,
                  const float* __restrict__ bdt, float* __restrict__ delta)
{
    __shared__ float sd[64];
    const int t = blockIdx.x;
    if (threadIdx.x < 64) sd[threadIdx.x] = xdbl[(size_t)t * 96 + threadIdx.x];
    __syncthreads();

    const int ch = blockIdx.y * 256 + threadIdx.x;
    const u16* wrow = Wdt + (size_t)ch * RNK;
    float acc = bdt[ch];
#pragma unroll
    for (int r = 0; r < RNK; r += 8) {
        uint4 wv = *(const uint4*)(wrow + r);
        float a0, a1, a2, a3, a4, a5, a6, a7;
        bf2x2(wv.x, a0, a1); bf2x2(wv.y, a2, a3);
        bf2x2(wv.z, a4, a5); bf2x2(wv.w, a6, a7);
        acc += sd[r]*a0 + sd[r+1]*a1 + sd[r+2]*a2 + sd[r+3]*a3
             + sd[r+4]*a4 + sd[r+5]*a5 + sd[r+6]*a6 + sd[r+7]*a7;
    }
    const float sp = (acc > 20.f) ? acc : log1pf(__expf(acc));
    delta[(size_t)t * DI + ch] = sp;
}

// ---------------------------------------------------------------------------
// Chunked selective scan. thread = channel; 16 states in registers.
// pass1: per chunk, h_local (h0=0) and a_prod = prod(dA). grid (DI/256, B*NC)
// ---------------------------------------------------------------------------
__global__ __launch_bounds__(256)
void scan_pass1(const float* __restrict__ delta, const float* __restrict__ xdbl,
                const u16* __restrict__ xc, const float* __restrict__ A_log,
                float* __restrict__ hfin, float* __restrict__ aprod)
{
    const int tid = threadIdx.x;
    const int ch  = blockIdx.x * 256 + tid;
    const int b   = blockIdx.y / NC;
    const int c   = blockIdx.y % NC;
    const int t0  = b * L_SZ + c * CLEN;

    __shared__ float sB[CLEN][16];
    for (int idx = tid; idx < CLEN * 16; idx += 256) {
        const int i = idx >> 4, nn = idx & 15;
        sB[i][nn] = xdbl[(size_t)(t0 + i) * 96 + 64 + nn];
    }

    float A[16];
    {
        const float4* Ar = (const float4*)(A_log + (size_t)ch * 16);
#pragma unroll
        for (int k = 0; k < 4; ++k) {
            const float4 v = Ar[k];
            A[4*k+0] = -__expf(v.x); A[4*k+1] = -__expf(v.y);
            A[4*k+2] = -__expf(v.z); A[4*k+3] = -__expf(v.w);
        }
    }
    __syncthreads();

    float h[16], P[16];
#pragma unroll
    for (int n = 0; n < 16; ++n) { h[n] = 0.f; P[n] = 1.f; }

    for (int i = 0; i < CLEN; ++i) {
        const size_t tok = (size_t)(t0 + i);
        const float d  = delta[tok * DI + ch];
        const float xv = bf2f(xc[tok * DI + ch]);
        const float dx = d * xv;
#pragma unroll
        for (int k = 0; k < 4; ++k) {
            const float4 Bv = *(const float4*)&sB[i][k * 4];
#pragma unroll
            for (int j = 0; j < 4; ++j) {
                const int n = k * 4 + j;
                const float Bj = (&Bv.x)[j];
                const float e = __expf(d * A[n]);
                h[n] = e * h[n] + dx * Bj;
                P[n] *= e;
            }
        }
    }

    float* hp = hfin  + ((size_t)(b * NC + c) * DI + ch) * 16;
    float* pp = aprod + ((size_t)(b * NC + c) * DI + ch) * 16;
#pragma unroll
    for (int k = 0; k < 4; ++k) {
        *(float4*)(hp + 4 * k) = (float4){h[4*k], h[4*k+1], h[4*k+2], h[4*k+3]};
        *(float4*)(pp + 4 * k) = (float4){P[4*k], P[4*k+1], P[4*k+2], P[4*k+3]};
    }
}

// ---------------------------------------------------------------------------
// combine: h0[c] = hfin[c-1] + aprod[c-1]*h0[c-1], h0[0]=0. thread=(b,ch,n)
// ---------------------------------------------------------------------------
__global__ __launch_bounds__(256)
void scan_combine(const float* __restrict__ hfin, const float* __restrict__ aprod,
                  float* __restrict__ h0buf)
{
    const int idx  = blockIdx.x * 256 + threadIdx.x;   // [0, B*DI*16)
    const int b    = idx >> 15;                         // DI*16 = 32768
    const int base = idx & 32767;
    float h0 = 0.f;
    for (int c = 0; c < NC; ++c) {
        const size_t o = (size_t)(b * NC + c) * 32768 + base;
        h0buf[o] = h0;
        h0 = hfin[o] + aprod[o] * h0;
    }
}

// ---------------------------------------------------------------------------
// pass2: full recurrence per chunk from h0; emits y. grid (DI/256, B*NC)
// ---------------------------------------------------------------------------
__global__ __launch_bounds__(256)
void scan_pass2(const float* __restrict__ delta, const float* __restrict__ xdbl,
                const u16* __restrict__ xc, const u16* __restrict__ sres,
                const float* __restrict__ A_log, const float* __restrict__ Dp,
                const float* __restrict__ h0buf, u16* __restrict__ yfin)
{
    const int tid = threadIdx.x;
    const int ch  = blockIdx.x * 256 + tid;
    const int b   = blockIdx.y / NC;
    const int c   = blockIdx.y % NC;
    const int t0  = b * L_SZ + c * CLEN;

    __shared__ float sB[CLEN][16], sC[CLEN][16];
    for (int idx = tid; idx < CLEN * 16; idx += 256) {
        const int i = idx >> 4, nn = idx & 15;
        sB[i][nn] = xdbl[(size_t)(t0 + i) * 96 + 64 + nn];
        sC[i][nn] = xdbl[(size_t)(t0 + i) * 96 + 80 + nn];
    }

    float A[16];
    {
        const float4* Ar = (const float4*)(A_log + (size_t)ch * 16);
#pragma unroll
        for (int k = 0; k < 4; ++k) {
            const float4 v = Ar[k];
            A[4*k+0] = -__expf(v.x); A[4*k+1] = -__expf(v.y);
            A[4*k+2] = -__expf(v.z); A[4*k+3] = -__expf(v.w);
        }
    }
    const float Dval = Dp[ch];

    float h[16];
    {
        const float4* hp = (const float4*)(h0buf + (size_t)(b * NC + c) * 32768 + (size_t)ch * 16);
#pragma unroll
        for (int k = 0; k < 4; ++k) {
            const float4 v = hp[k];
            h[4*k+0] = v.x; h[4*k+1] = v.y; h[4*k+2] = v.z; h[4*k+3] = v.w;
        }
    }
    __syncthreads();

    for (int i = 0; i < CLEN; ++i) {
        const size_t tok = (size_t)(t0 + i);
        const float d  = delta[tok * DI + ch];
        const float xv = bf2f(xc[tok * DI + ch]);
        const float rv = bf2f(sres[tok * DI + ch]);
        const float dx = d * xv;
        float acc0 = 0.f, acc1 = 0.f, acc2 = 0.f, acc3 = 0.f;
#pragma unroll
        for (int k = 0; k < 4; ++k) {
            const float4 Bv = *(const float4*)&sB[i][k * 4];
            const float4 Cv = *(const float4*)&sC[i][k * 4];
#pragma unroll
            for (int j = 0; j < 4; ++j) {
                const int n = k * 4 + j;
                const float e = __expf(d * A[n]);
                h[n] = e * h[n] + dx * (&Bv.x)[j];
                const float t = h[n] * (&Cv.x)[j];
                if (j == 0) acc0 += t; else if (j == 1) acc1 += t;
                else if (j == 2) acc2 += t; else acc3 += t;
            }
        }
        const float p = (acc0 + acc1) + (acc2 + acc3);
        const float y = (p + Dval * xv) * rv;
        yfin[tok * DI + ch] = f2bf(y);
    }
}

// ---------------------------------------------------------------------------
extern "C" void kernel_launch(void* const* d_in, const int* in_sizes, int n_in,
                              void* d_out, int out_size, void* d_ws, size_t ws_size,
                              hipStream_t stream)
{
    const float* x      = (const float*)d_in[0];
    const float* W_in   = (const float*)d_in[1];
    const float* conv_w = (const float*)d_in[2];
    const float* conv_b = (const float*)d_in[3];
    const float* W_x    = (const float*)d_in[4];
    const float* W_dt   = (const float*)d_in[5];
    const float* b_dt   = (const float*)d_in[6];
    const float* A_log  = (const float*)d_in[7];
    const float* D_par  = (const float*)d_in[8];
    const float* W_out  = (const float*)d_in[9];
    float* out = (float*)d_out;

    char* ws = (char*)d_ws;
    size_t off = 0;
    u16* xb    = (u16*)(ws + off); off += (size_t)TOK * DM * 2;        //  8.4 MB
    u16* Winb  = (u16*)(ws + off); off += (size_t)(2 * DI) * DM * 2;   //  8.4 MB
    u16* Woutb = (u16*)(ws + off); off += (size_t)DM * DI * 2;         //  4.2 MB
    u16* Wxb   = (u16*)(ws + off); off += (size_t)96 * DI * 2;         //  0.4 MB
    u16* Wdtb  = (u16*)(ws + off); off += (size_t)DI * RNK * 2;        //  0.3 MB
    u16* xm    = (u16*)(ws + off); off += (size_t)TOK * DI * 2;        // 16.8 MB
    u16* xc    = (u16*)(ws + off); off += (size_t)TOK * DI * 2;        // 16.8 MB
    u16* sres  = (u16*)(ws + off); off += (size_t)TOK * DI * 2;        // 16.8 MB
    float* xdbl  = (float*)(ws + off); off += (size_t)TOK * 96 * 4;    //  1.6 MB
    float* delta = (float*)(ws + off); off += (size_t)TOK * DI * 4;    // 33.6 MB
    float* hfin  = (float*)(ws + off); off += (size_t)NC * B_SZ * DI * NST * 4; // 8.4 MB
    float* aprod = (float*)(ws + off); off += (size_t)NC * B_SZ * DI * NST * 4; // 8.4 MB
    float* h0buf = (float*)(ws + off); off += (size_t)NC * B_SZ * DI * NST * 4; // 8.4 MB
    u16* yfin = xm;   // xm is dead after conv_silu_kernel — reuse

    // 0. convert GEMM operands f32 -> bf16
    cvt_f2b<<<(TOK * DM / 4 + 255) / 256, 256, 0, stream>>>(x, xb, TOK * DM / 4);
    cvt_f2b<<<(2 * DI * DM / 4 + 255) / 256, 256, 0, stream>>>(W_in, Winb, 2 * DI * DM / 4);
    cvt_f2b<<<(DM * DI / 4 + 255) / 256, 256, 0, stream>>>(W_out, Woutb, DM * DI / 4);
    cvt_f2b<<<(96 * DI / 4 + 255) / 256, 256, 0, stream>>>(W_x, Wxb, 96 * DI / 4);
    cvt_f2b<<<(DI * RNK / 4 + 255) / 256, 256, 0, stream>>>(W_dt, Wdtb, DI * RNK / 4);

    // 1. in_proj
    gemm_bt<1><<<dim3(TOK / 128, (2 * DI) / 128), 256, 0, stream>>>(
        xb, Winb, DM, 2 * DI, xm, sres, nullptr);

    // 2. causal depthwise conv + silu
    conv_silu_kernel<<<(TOK * DI) / 256, 256, 0, stream>>>(xm, conv_w, conv_b, xc);

    // 3. x_dbl = xc @ W_x^T
    xdbl_kernel<<<TOK, 256, 0, stream>>>(xc, Wxb, xdbl);

    // 4. delta = softplus(dlt @ W_dt^T + b_dt)
    delta_kernel<<<dim3(TOK, DI / 256), 256, 0, stream>>>(xdbl, Wdtb, b_dt, delta);

    // 5. chunked selective scan
    scan_pass1<<<dim3(DI / 256, B_SZ * NC), 256, 0, stream>>>(
        delta, xdbl, xc, A_log, hfin, aprod);
    scan_combine<<<(B_SZ * DI * NST) / 256, 256, 0, stream>>>(hfin, aprod, h0buf);
    scan_pass2<<<dim3(DI / 256, B_SZ * NC), 256, 0, stream>>>(
        delta, xdbl, xc, sres, A_log, D_par, h0buf, yfin);

    // 6. out = yfin @ W_out^T (f32 store)
    gemm_bt<0><<<dim3(TOK / 128, DM / 128), 256, 0, stream>>>(
        yfin, Woutb, DI, DM, nullptr, nullptr, out);
}

// Round 4
// 452.856 us; speedup vs baseline: 2.1327x; 1.3700x over previous
//
#include <hip/hip_runtime.h>

typedef unsigned short u16;
typedef __attribute__((ext_vector_type(8))) short bf16x8;
typedef __attribute__((ext_vector_type(4))) float f32x4;

#define B_SZ   2
#define L_SZ   2048
#define DM     1024
#define DI     2048
#define NST    16
#define RNK    64
#define TOK    (B_SZ * L_SZ)   // 4096
#define NC     32              // scan chunks
#define CLEN   (L_SZ / NC)     // 64 steps per chunk
#define XDS    128             // x_dbl row stride (padded from 96)
#define KSPL   8               // K-split for xdbl gemm

__device__ __forceinline__ float bf2f(u16 u) {
    return __uint_as_float(((unsigned int)u) << 16);
}
__device__ __forceinline__ u16 f2bf(float f) {
    unsigned int x = __float_as_uint(f);
    x += 0x7fffu + ((x >> 16) & 1u);   // RNE
    return (u16)(x >> 16);
}
__device__ __forceinline__ void bf2x2(unsigned int p, float& lo, float& hi) {
    lo = __uint_as_float(p << 16);
    hi = __uint_as_float(p & 0xffff0000u);
}
__device__ __forceinline__ float silu(float v) {
    return v / (1.f + __expf(-v));
}

// ---------------------------------------------------------------------------
// f32 -> bf16 conversion (vectorized x4); n4 = elements/4
// ---------------------------------------------------------------------------
__global__ __launch_bounds__(256)
void cvt_f2b(const float* __restrict__ src, u16* __restrict__ dst, int n4)
{
    const int i = blockIdx.x * 256 + threadIdx.x;
    if (i < n4) {
        const float4 v = ((const float4*)src)[i];
        ushort4 o;
        o.x = f2bf(v.x); o.y = f2bf(v.y); o.z = f2bf(v.z); o.w = f2bf(v.w);
        ((ushort4*)dst)[i] = o;
    }
}

// W_x [96 x 2048] f32 -> [128 x 2048] bf16, rows 96..127 zeroed
__global__ __launch_bounds__(256)
void cvt_wx(const float* __restrict__ src, u16* __restrict__ dst)
{
    const int i = blockIdx.x * 256 + threadIdx.x;   // [0, 128*2048/4)
    const int row = (i * 4) >> 11;
    ushort4 o;
    if (row < 96) {
        const float4 v = ((const float4*)src)[i];
        o.x = f2bf(v.x); o.y = f2bf(v.y); o.z = f2bf(v.z); o.w = f2bf(v.w);
    } else {
        o.x = o.y = o.z = o.w = 0;
    }
    ((ushort4*)dst)[i] = o;
}

// ---------------------------------------------------------------------------
// GEMM  C[M][N] = A[M][K] @ B[N][K]^T   (both operands K-contiguous bf16)
// 128x128 tile, BK=32, 4 waves (2x2 of 64x64), mfma_f32_16x16x32_bf16.
// EPI==0: plain f32 store to outF (ld = N)   [final out_proj]
// EPI==1: in_proj epilogue: col<DI -> out0=x_m (bf16); col>=DI -> out1=silu (bf16)
// ---------------------------------------------------------------------------
template<int EPI>
__global__ __launch_bounds__(256, 2)
void gemm_bt(const u16* __restrict__ A, const u16* __restrict__ B,
             const int K, const int N,
             u16* __restrict__ out0, u16* __restrict__ out1,
             float* __restrict__ outF)
{
    __shared__ u16 sA[128 * 40];
    __shared__ u16 sB[128 * 40];

    const int tid  = threadIdx.x;
    const int rowBase = blockIdx.x << 7;
    const int colBase = blockIdx.y << 7;
    const int wave = tid >> 6, lane = tid & 63;
    const int wm = (wave >> 1) << 6;
    const int wn = (wave & 1) << 6;
    const int lrow = lane & 15, quad = lane >> 4;

    const int sr  = tid >> 2;
    const int skc = tid & 3;
    const u16* Ap = A + (size_t)(rowBase + sr) * K + skc * 8;
    const u16* Bp = B + (size_t)(colBase + sr) * K + skc * 8;
    const size_t rowJump = (size_t)64 * K;
    const int sLds = sr * 40 + skc * 8;

    f32x4 acc[4][4];
#pragma unroll
    for (int i = 0; i < 4; ++i)
#pragma unroll
        for (int j = 0; j < 4; ++j) acc[i][j] = (f32x4){0.f, 0.f, 0.f, 0.f};

    uint4 pa0 = *(const uint4*)(Ap);
    uint4 pa1 = *(const uint4*)(Ap + rowJump);
    uint4 pb0 = *(const uint4*)(Bp);
    uint4 pb1 = *(const uint4*)(Bp + rowJump);

    const int KT = K >> 5;
    for (int kt = 0; kt < KT; ++kt) {
        *(uint4*)&sA[sLds]           = pa0;
        *(uint4*)&sA[sLds + 64 * 40] = pa1;
        *(uint4*)&sB[sLds]           = pb0;
        *(uint4*)&sB[sLds + 64 * 40] = pb1;
        __syncthreads();

        if (kt + 1 < KT) {
            const int ko = (kt + 1) * 32;
            pa0 = *(const uint4*)(Ap + ko);
            pa1 = *(const uint4*)(Ap + ko + rowJump);
            pb0 = *(const uint4*)(Bp + ko);
            pb1 = *(const uint4*)(Bp + ko + rowJump);
        }

        bf16x8 af[4], bfr[4];
#pragma unroll
        for (int i = 0; i < 4; ++i)
            af[i] = *(const bf16x8*)&sA[(wm + i * 16 + lrow) * 40 + quad * 8];
#pragma unroll
        for (int j = 0; j < 4; ++j)
            bfr[j] = *(const bf16x8*)&sB[(wn + j * 16 + lrow) * 40 + quad * 8];

#pragma unroll
        for (int i = 0; i < 4; ++i)
#pragma unroll
            for (int j = 0; j < 4; ++j)
                acc[i][j] = __builtin_amdgcn_mfma_f32_16x16x32_bf16(
                    af[i], bfr[j], acc[i][j], 0, 0, 0);
        __syncthreads();
    }

#pragma unroll
    for (int i = 0; i < 4; ++i) {
#pragma unroll
        for (int j = 0; j < 4; ++j) {
            const int gcol = colBase + wn + j * 16 + lrow;
#pragma unroll
            for (int r = 0; r < 4; ++r) {
                const int grow = rowBase + wm + i * 16 + quad * 4 + r;
                const float v = acc[i][j][r];
                if (EPI == 0) {
                    outF[(size_t)grow * N + gcol] = v;
                } else {
                    if (gcol < DI) out0[(size_t)grow * DI + gcol] = f2bf(v);
                    else           out1[(size_t)grow * DI + (gcol - DI)] = f2bf(silu(v));
                }
            }
        }
    }
}

// ---------------------------------------------------------------------------
// xdbl GEMM: part[ks][128 tokens][128] = xc_tile @ WxP^T over K-slice ks*256.
// grid (TOK/128, KSPL). Same tile structure as gemm_bt.
// ---------------------------------------------------------------------------
__global__ __launch_bounds__(256, 2)
void gemm_xdbl(const u16* __restrict__ A, const u16* __restrict__ B,
               float* __restrict__ part)
{
    __shared__ u16 sA[128 * 40];
    __shared__ u16 sB[128 * 40];

    const int tid  = threadIdx.x;
    const int rowBase = blockIdx.x << 7;
    const int ks   = blockIdx.y;
    const int k0   = ks * (DI / KSPL);          // 256-elem K slice
    const int wave = tid >> 6, lane = tid & 63;
    const int wm = (wave >> 1) << 6;
    const int wn = (wave & 1) << 6;
    const int lrow = lane & 15, quad = lane >> 4;

    const int sr  = tid >> 2;
    const int skc = tid & 3;
    const u16* Ap = A + (size_t)(rowBase + sr) * DI + k0 + skc * 8;
    const u16* Bp = B + (size_t)sr * DI + k0 + skc * 8;
    const size_t rowJump = (size_t)64 * DI;
    const int sLds = sr * 40 + skc * 8;

    f32x4 acc[4][4];
#pragma unroll
    for (int i = 0; i < 4; ++i)
#pragma unroll
        for (int j = 0; j < 4; ++j) acc[i][j] = (f32x4){0.f, 0.f, 0.f, 0.f};

    uint4 pa0 = *(const uint4*)(Ap);
    uint4 pa1 = *(const uint4*)(Ap + rowJump);
    uint4 pb0 = *(const uint4*)(Bp);
    uint4 pb1 = *(const uint4*)(Bp + rowJump);

    const int KT = (DI / KSPL) >> 5;            // 8
    for (int kt = 0; kt < KT; ++kt) {
        *(uint4*)&sA[sLds]           = pa0;
        *(uint4*)&sA[sLds + 64 * 40] = pa1;
        *(uint4*)&sB[sLds]           = pb0;
        *(uint4*)&sB[sLds + 64 * 40] = pb1;
        __syncthreads();

        if (kt + 1 < KT) {
            const int ko = (kt + 1) * 32;
            pa0 = *(const uint4*)(Ap + ko);
            pa1 = *(const uint4*)(Ap + ko + rowJump);
            pb0 = *(const uint4*)(Bp + ko);
            pb1 = *(const uint4*)(Bp + ko + rowJump);
        }

        bf16x8 af[4], bfr[4];
#pragma unroll
        for (int i = 0; i < 4; ++i)
            af[i] = *(const bf16x8*)&sA[(wm + i * 16 + lrow) * 40 + quad * 8];
#pragma unroll
        for (int j = 0; j < 4; ++j)
            bfr[j] = *(const bf16x8*)&sB[(wn + j * 16 + lrow) * 40 + quad * 8];

#pragma unroll
        for (int i = 0; i < 4; ++i)
#pragma unroll
            for (int j = 0; j < 4; ++j)
                acc[i][j] = __builtin_amdgcn_mfma_f32_16x16x32_bf16(
                    af[i], bfr[j], acc[i][j], 0, 0, 0);
        __syncthreads();
    }

    float* base = part + (size_t)ks * TOK * XDS;
#pragma unroll
    for (int i = 0; i < 4; ++i) {
#pragma unroll
        for (int j = 0; j < 4; ++j) {
            const int gcol = wn + j * 16 + lrow;
#pragma unroll
            for (int r = 0; r < 4; ++r) {
                const int grow = rowBase + wm + i * 16 + quad * 4 + r;
                base[(size_t)grow * XDS + gcol] = acc[i][j][r];
            }
        }
    }
}

// sum the 8 K-slice partials -> xdblP [TOK x 128] f32
__global__ __launch_bounds__(256)
void reduce_part(const float4* __restrict__ part, float4* __restrict__ xdbl)
{
    const int i = blockIdx.x * 256 + threadIdx.x;   // [0, TOK*XDS/4)
    const int n4 = TOK * XDS / 4;
    float4 s = part[i];
#pragma unroll
    for (int ks = 1; ks < KSPL; ++ks) {
        const float4 v = part[(size_t)ks * n4 + i];
        s.x += v.x; s.y += v.y; s.z += v.z; s.w += v.w;
    }
    xdbl[i] = s;
}

// ---------------------------------------------------------------------------
// causal depthwise conv (K=4) + silu
// ---------------------------------------------------------------------------
__global__ __launch_bounds__(256)
void conv_silu_kernel(const u16* __restrict__ xm, const float* __restrict__ cw,
                      const float* __restrict__ cb, u16* __restrict__ xc)
{
    const int idx = blockIdx.x * 256 + threadIdx.x;
    const int ch = idx & (DI - 1);
    const int t  = idx >> 11;
    const int l  = t & (L_SZ - 1);

    const float4 wv = *(const float4*)(cw + ch * 4);

    float acc = cb[ch];
    if (l >= 3) acc += wv.x * bf2f(xm[(size_t)(t - 3) * DI + ch]);
    if (l >= 2) acc += wv.y * bf2f(xm[(size_t)(t - 2) * DI + ch]);
    if (l >= 1) acc += wv.z * bf2f(xm[(size_t)(t - 1) * DI + ch]);
    acc += wv.w * bf2f(xm[(size_t)t * DI + ch]);

    xc[idx] = f2bf(silu(acc));
}

// ---------------------------------------------------------------------------
// delta[t][ch] = softplus(xdbl[t][0:64] @ W_dt[ch][:]^T + b_dt[ch])
// ---------------------------------------------------------------------------
__global__ __launch_bounds__(256)
void delta_kernel(const float* __restrict__ xdbl, const u16* __restrict__ Wdt,
                  const float* __restrict__ bdt, float* __restrict__ delta)
{
    __shared__ float sd[64];
    const int t = blockIdx.x;
    if (threadIdx.x < 64) sd[threadIdx.x] = xdbl[(size_t)t * XDS + threadIdx.x];
    __syncthreads();

    const int ch = blockIdx.y * 256 + threadIdx.x;
    const u16* wrow = Wdt + (size_t)ch * RNK;
    float acc = bdt[ch];
#pragma unroll
    for (int r = 0; r < RNK; r += 8) {
        uint4 wv = *(const uint4*)(wrow + r);
        float a0, a1, a2, a3, a4, a5, a6, a7;
        bf2x2(wv.x, a0, a1); bf2x2(wv.y, a2, a3);
        bf2x2(wv.z, a4, a5); bf2x2(wv.w, a6, a7);
        acc += sd[r]*a0 + sd[r+1]*a1 + sd[r+2]*a2 + sd[r+3]*a3
             + sd[r+4]*a4 + sd[r+5]*a5 + sd[r+6]*a6 + sd[r+7]*a7;
    }
    const float sp = (acc > 20.f) ? acc : log1pf(__expf(acc));
    delta[(size_t)t * DI + ch] = sp;
}

// ---------------------------------------------------------------------------
// Chunked selective scan. thread = channel; 16 states in registers.
// ---------------------------------------------------------------------------
__global__ __launch_bounds__(256)
void scan_pass1(const float* __restrict__ delta, const float* __restrict__ xdbl,
                const u16* __restrict__ xc, const float* __restrict__ A_log,
                float* __restrict__ hfin, float* __restrict__ aprod)
{
    const int tid = threadIdx.x;
    const int ch  = blockIdx.x * 256 + tid;
    const int b   = blockIdx.y / NC;
    const int c   = blockIdx.y % NC;
    const int t0  = b * L_SZ + c * CLEN;

    __shared__ float sB[CLEN][16];
    for (int idx = tid; idx < CLEN * 16; idx += 256) {
        const int i = idx >> 4, nn = idx & 15;
        sB[i][nn] = xdbl[(size_t)(t0 + i) * XDS + 64 + nn];
    }

    float A[16];
    {
        const float4* Ar = (const float4*)(A_log + (size_t)ch * 16);
#pragma unroll
        for (int k = 0; k < 4; ++k) {
            const float4 v = Ar[k];
            A[4*k+0] = -__expf(v.x); A[4*k+1] = -__expf(v.y);
            A[4*k+2] = -__expf(v.z); A[4*k+3] = -__expf(v.w);
        }
    }
    __syncthreads();

    float h[16], P[16];
#pragma unroll
    for (int n = 0; n < 16; ++n) { h[n] = 0.f; P[n] = 1.f; }

    for (int i = 0; i < CLEN; ++i) {
        const size_t tok = (size_t)(t0 + i);
        const float d  = delta[tok * DI + ch];
        const float xv = bf2f(xc[tok * DI + ch]);
        const float dx = d * xv;
#pragma unroll
        for (int k = 0; k < 4; ++k) {
            const float4 Bv = *(const float4*)&sB[i][k * 4];
#pragma unroll
            for (int j = 0; j < 4; ++j) {
                const int n = k * 4 + j;
                const float e = __expf(d * A[n]);
                h[n] = e * h[n] + dx * (&Bv.x)[j];
                P[n] *= e;
            }
        }
    }

    float* hp = hfin  + ((size_t)(b * NC + c) * DI + ch) * 16;
    float* pp = aprod + ((size_t)(b * NC + c) * DI + ch) * 16;
#pragma unroll
    for (int k = 0; k < 4; ++k) {
        *(float4*)(hp + 4 * k) = (float4){h[4*k], h[4*k+1], h[4*k+2], h[4*k+3]};
        *(float4*)(pp + 4 * k) = (float4){P[4*k], P[4*k+1], P[4*k+2], P[4*k+3]};
    }
}

__global__ __launch_bounds__(256)
void scan_combine(const float* __restrict__ hfin, const float* __restrict__ aprod,
                  float* __restrict__ h0buf)
{
    const int idx  = blockIdx.x * 256 + threadIdx.x;
    const int b    = idx >> 15;
    const int base = idx & 32767;
    float h0 = 0.f;
    for (int c = 0; c < NC; ++c) {
        const size_t o = (size_t)(b * NC + c) * 32768 + base;
        h0buf[o] = h0;
        h0 = hfin[o] + aprod[o] * h0;
    }
}

__global__ __launch_bounds__(256)
void scan_pass2(const float* __restrict__ delta, const float* __restrict__ xdbl,
                const u16* __restrict__ xc, const u16* __restrict__ sres,
                const float* __restrict__ A_log, const float* __restrict__ Dp,
                const float* __restrict__ h0buf, u16* __restrict__ yfin)
{
    const int tid = threadIdx.x;
    const int ch  = blockIdx.x * 256 + tid;
    const int b   = blockIdx.y / NC;
    const int c   = blockIdx.y % NC;
    const int t0  = b * L_SZ + c * CLEN;

    __shared__ float sB[CLEN][16], sC[CLEN][16];
    for (int idx = tid; idx < CLEN * 16; idx += 256) {
        const int i = idx >> 4, nn = idx & 15;
        sB[i][nn] = xdbl[(size_t)(t0 + i) * XDS + 64 + nn];
        sC[i][nn] = xdbl[(size_t)(t0 + i) * XDS + 80 + nn];
    }

    float A[16];
    {
        const float4* Ar = (const float4*)(A_log + (size_t)ch * 16);
#pragma unroll
        for (int k = 0; k < 4; ++k) {
            const float4 v = Ar[k];
            A[4*k+0] = -__expf(v.x); A[4*k+1] = -__expf(v.y);
            A[4*k+2] = -__expf(v.z); A[4*k+3] = -__expf(v.w);
        }
    }
    const float Dval = Dp[ch];

    float h[16];
    {
        const float4* hp = (const float4*)(h0buf + (size_t)(b * NC + c) * 32768 + (size_t)ch * 16);
#pragma unroll
        for (int k = 0; k < 4; ++k) {
            const float4 v = hp[k];
            h[4*k+0] = v.x; h[4*k+1] = v.y; h[4*k+2] = v.z; h[4*k+3] = v.w;
        }
    }
    __syncthreads();

    for (int i = 0; i < CLEN; ++i) {
        const size_t tok = (size_t)(t0 + i);
        const float d  = delta[tok * DI + ch];
        const float xv = bf2f(xc[tok * DI + ch]);
        const float rv = bf2f(sres[tok * DI + ch]);
        const float dx = d * xv;
        float acc0 = 0.f, acc1 = 0.f, acc2 = 0.f, acc3 = 0.f;
#pragma unroll
        for (int k = 0; k < 4; ++k) {
            const float4 Bv = *(const float4*)&sB[i][k * 4];
            const float4 Cv = *(const float4*)&sC[i][k * 4];
#pragma unroll
            for (int j = 0; j < 4; ++j) {
                const int n = k * 4 + j;
                const float e = __expf(d * A[n]);
                h[n] = e * h[n] + dx * (&Bv.x)[j];
                const float t = h[n] * (&Cv.x)[j];
                if (j == 0) acc0 += t; else if (j == 1) acc1 += t;
                else if (j == 2) acc2 += t; else acc3 += t;
            }
        }
        const float p = (acc0 + acc1) + (acc2 + acc3);
        const float y = (p + Dval * xv) * rv;
        yfin[tok * DI + ch] = f2bf(y);
    }
}

// ---------------------------------------------------------------------------
extern "C" void kernel_launch(void* const* d_in, const int* in_sizes, int n_in,
                              void* d_out, int out_size, void* d_ws, size_t ws_size,
                              hipStream_t stream)
{
    const float* x      = (const float*)d_in[0];
    const float* W_in   = (const float*)d_in[1];
    const float* conv_w = (const float*)d_in[2];
    const float* conv_b = (const float*)d_in[3];
    const float* W_x    = (const float*)d_in[4];
    const float* W_dt   = (const float*)d_in[5];
    const float* b_dt   = (const float*)d_in[6];
    const float* A_log  = (const float*)d_in[7];
    const float* D_par  = (const float*)d_in[8];
    const float* W_out  = (const float*)d_in[9];
    float* out = (float*)d_out;

    char* ws = (char*)d_ws;
    size_t off = 0;
    u16* xb    = (u16*)(ws + off); off += (size_t)TOK * DM * 2;        //  8.4 MB
    u16* Winb  = (u16*)(ws + off); off += (size_t)(2 * DI) * DM * 2;   //  8.4 MB
    u16* Woutb = (u16*)(ws + off); off += (size_t)DM * DI * 2;         //  4.2 MB
    u16* Wxb   = (u16*)(ws + off); off += (size_t)XDS * DI * 2;        //  0.5 MB (padded)
    u16* Wdtb  = (u16*)(ws + off); off += (size_t)DI * RNK * 2;        //  0.3 MB
    u16* xm    = (u16*)(ws + off); off += (size_t)TOK * DI * 2;        // 16.8 MB
    u16* xc    = (u16*)(ws + off); off += (size_t)TOK * DI * 2;        // 16.8 MB
    u16* sres  = (u16*)(ws + off); off += (size_t)TOK * DI * 2;        // 16.8 MB
    float* xdblP = (float*)(ws + off); off += (size_t)TOK * XDS * 4;   //  2.1 MB
    float* delta = (float*)(ws + off); off += (size_t)TOK * DI * 4;    // 33.6 MB
    float* hfin  = (float*)(ws + off); off += (size_t)NC * B_SZ * DI * NST * 4; // 8.4 MB
    float* aprod = (float*)(ws + off); off += (size_t)NC * B_SZ * DI * NST * 4; // 8.4 MB
    float* h0buf = (float*)(ws + off); off += (size_t)NC * B_SZ * DI * NST * 4; // 8.4 MB
    u16* yfin = xm;              // xm dead after conv — reuse
    float* part = hfin;          // hfin+aprod (16.8 MB) dead until scan_pass1 — reuse for K-split partials

    // 0. convert GEMM operands f32 -> bf16
    cvt_f2b<<<(TOK * DM / 4 + 255) / 256, 256, 0, stream>>>(x, xb, TOK * DM / 4);
    cvt_f2b<<<(2 * DI * DM / 4 + 255) / 256, 256, 0, stream>>>(W_in, Winb, 2 * DI * DM / 4);
    cvt_f2b<<<(DM * DI / 4 + 255) / 256, 256, 0, stream>>>(W_out, Woutb, DM * DI / 4);
    cvt_wx<<<(XDS * DI / 4) / 256, 256, 0, stream>>>(W_x, Wxb);
    cvt_f2b<<<(DI * RNK / 4 + 255) / 256, 256, 0, stream>>>(W_dt, Wdtb, DI * RNK / 4);

    // 1. in_proj
    gemm_bt<1><<<dim3(TOK / 128, (2 * DI) / 128), 256, 0, stream>>>(
        xb, Winb, DM, 2 * DI, xm, sres, nullptr);

    // 2. causal depthwise conv + silu
    conv_silu_kernel<<<(TOK * DI) / 256, 256, 0, stream>>>(xm, conv_w, conv_b, xc);

    // 3. x_dbl = xc @ W_x^T  (MFMA, K-split 8, then reduce)
    gemm_xdbl<<<dim3(TOK / 128, KSPL), 256, 0, stream>>>(xc, Wxb, part);
    reduce_part<<<(TOK * XDS / 4) / 256, 256, 0, stream>>>(
        (const float4*)part, (float4*)xdblP);

    // 4. delta = softplus(dlt @ W_dt^T + b_dt)
    delta_kernel<<<dim3(TOK, DI / 256), 256, 0, stream>>>(xdblP, Wdtb, b_dt, delta);

    // 5. chunked selective scan
    scan_pass1<<<dim3(DI / 256, B_SZ * NC), 256, 0, stream>>>(
        delta, xdblP, xc, A_log, hfin, aprod);
    scan_combine<<<(B_SZ * DI * NST) / 256, 256, 0, stream>>>(hfin, aprod, h0buf);
    scan_pass2<<<dim3(DI / 256, B_SZ * NC), 256, 0, stream>>>(
        delta, xdblP, xc, sres, A_log, D_par, h0buf, yfin);

    // 6. out = yfin @ W_out^T (f32 store)
    gemm_bt<0><<<dim3(TOK / 128, DM / 128), 256, 0, stream>>>(
        yfin, Woutb, DI, DM, nullptr, nullptr, out);
}